// Round 8
// baseline (240.151 us; speedup 1.0000x reference)
//
#include <hip/hip_runtime.h>
#include <hip/hip_bf16.h>

#define DIM 2048
#define S_LEN 2048
#define N_HEADS 32
#define N_KV_HEADS 8
#define HEAD_DIM 64
#define KV_DIM (N_KV_HEADS * HEAD_DIM)   // 512
#define QKV_N (DIM + 2 * KV_DIM)         // 3072
#define QSCALE 0.18033688011112042f      // 0.125 * log2(e), folded into Q at rope

typedef __attribute__((ext_vector_type(8))) short bf16x8;
typedef __attribute__((ext_vector_type(4))) float f32x4;

__device__ __forceinline__ unsigned short bf16_of(float f) {
    __hip_bfloat16 h = __float2bfloat16(f);
    return *reinterpret_cast<unsigned short*>(&h);
}
__device__ __forceinline__ float f_of_bf16(unsigned short u) {
    unsigned int x = ((unsigned int)u) << 16;
    return __uint_as_float(x);
}
__device__ __forceinline__ void gl_lds16(const void* g, void* l) {
    __builtin_amdgcn_global_load_lds((const __attribute__((address_space(1))) void*)g,
                                     (__attribute__((address_space(3))) void*)l, 16, 0, 0);
}
// pack two fp32 -> bf16x2 by truncation: one v_perm_b32
__device__ __forceinline__ unsigned int pack2tr(float lo, float hi) {
    return __builtin_amdgcn_perm(__float_as_uint(hi), __float_as_uint(lo), 0x07060302u);
}
// 3-input max in one VALU op (T17)
__device__ __forceinline__ float max3f(float a, float b, float c) {
    float d;
    asm("v_max3_f32 %0, %1, %2, %3" : "=v"(d) : "v"(a), "v"(b), "v"(c));
    return d;
}

// ---------------------------------------------------------------------------
// prep: fused x->bf16 convert (blocks 0..4095) + 4 weight transpose/converts
// (blocks 4096..6655).  All weight transposes land in [N][K=2048] bf16.
// Transpose leg vectorized: float4 loads, ushort4 stores.
// ---------------------------------------------------------------------------
__global__ __launch_bounds__(256) void prep(const float* __restrict__ x,
                                            const float* __restrict__ wq,
                                            const float* __restrict__ wk,
                                            const float* __restrict__ wv,
                                            const float* __restrict__ wo,
                                            unsigned short* __restrict__ xbf,
                                            unsigned short* __restrict__ wqkvT,
                                            unsigned short* __restrict__ woT) {
    __shared__ float tile[64][65];
    const int t = threadIdx.x;
    int b = blockIdx.x;
    if (b < 4096) {
        int idx = b * 256 + t;
        float4 f = ((const float4*)x)[idx];
        ushort4 u;
        u.x = bf16_of(f.x); u.y = bf16_of(f.y); u.z = bf16_of(f.z); u.w = bf16_of(f.w);
        ((ushort4*)xbf)[idx] = u;
        return;
    }
    b -= 4096;
    const float* src;
    unsigned short* dst;
    int src_cols, bx, by;
    if (b < 1024)      { src = wq; dst = wqkvT;                                src_cols = DIM;    bx = b & 31;          by = b >> 5; }
    else if (b < 1280) { src = wk; dst = wqkvT + (size_t)DIM * DIM;            src_cols = KV_DIM; bx = (b - 1024) & 7;  by = (b - 1024) >> 3; }
    else if (b < 1536) { src = wv; dst = wqkvT + (size_t)(DIM + KV_DIM) * DIM; src_cols = KV_DIM; bx = (b - 1280) & 7;  by = (b - 1280) >> 3; }
    else               { src = wo; dst = woT;                                  src_cols = DIM;    bx = (b - 1536) & 31; by = (b - 1536) >> 5; }
    const int c0 = bx * 64, r0 = by * 64;
#pragma unroll
    for (int i = 0; i < 4; i++) {
        int idx = t + i * 256;
        int r = idx >> 4, c4 = (idx & 15) * 4;
        float4 f = *(const float4*)&src[(size_t)(r0 + r) * src_cols + c0 + c4];
        tile[r][c4 + 0] = f.x; tile[r][c4 + 1] = f.y;
        tile[r][c4 + 2] = f.z; tile[r][c4 + 3] = f.w;
    }
    __syncthreads();
#pragma unroll
    for (int i = 0; i < 4; i++) {
        int idx = t + i * 256;
        int rr = idx >> 4, cc = (idx & 15) * 4;
        ushort4 u;
        u.x = bf16_of(tile[cc + 0][rr]);
        u.y = bf16_of(tile[cc + 1][rr]);
        u.z = bf16_of(tile[cc + 2][rr]);
        u.w = bf16_of(tile[cc + 3][rr]);
        *(ushort4*)&dst[(size_t)(c0 + rr) * DIM + r0 + cc] = u;
    }
}

// ---------------------------------------------------------------------------
// bf16 MFMA GEMM, 128(M) x 64(N) tile, BK=64, 4 waves (2x2, each 64x32).
// Two-stage single-barrier dbuf (proven best).  LDS 48KB -> 3 blocks/CU.
// (3-stage counted-vmcnt measured WORSE (59 vs 40us).  Do not revisit.)
// ---------------------------------------------------------------------------
__global__ __launch_bounds__(256) void gemm_bt64(const unsigned short* __restrict__ A,
                                                 const unsigned short* __restrict__ Bt,
                                                 void* __restrict__ Cv,
                                                 int M, int N, int K, int c_bf16) {
    __shared__ unsigned short As[2][128 * 64];
    __shared__ unsigned short Bs[2][64 * 64];
    const int tid = threadIdx.x;
    const int wave = tid >> 6, lane = tid & 63;
    const int m16 = lane & 15, quad = lane >> 4;
    const int m0 = blockIdx.y * 128, n0 = blockIdx.x * 64;
    const int wm = (wave >> 1) * 64, wn = (wave & 1) * 32;

    const int lrow = lane >> 3;
    const int gc = (lane & 7) ^ lrow;
    const unsigned short* Ab = A + (size_t)(m0 + wave * 8 + lrow) * K + gc * 8;
    const unsigned short* Bb = Bt + (size_t)(n0 + wave * 8 + lrow) * K + gc * 8;

    f32x4 acc[4][2];
#pragma unroll
    for (int mb = 0; mb < 4; mb++)
#pragma unroll
        for (int nb = 0; nb < 2; nb++) acc[mb][nb] = (f32x4){0.f, 0.f, 0.f, 0.f};

    // prologue: stage tile 0 into buffer 0
#pragma unroll
    for (int g = 0; g < 4; g++)
        gl_lds16(Ab + (size_t)g * 32 * K, &As[0][(g * 32 + wave * 8) * 64]);
#pragma unroll
    for (int g = 0; g < 2; g++)
        gl_lds16(Bb + (size_t)g * 32 * K, &Bs[0][(g * 32 + wave * 8) * 64]);

    const int nt = K >> 6;
    for (int kt = 0; kt < nt; kt++) {
        __syncthreads();                 // drain own DMA (vmcnt0) + prev reads done
        if (kt + 1 < nt) {
            const int nb2 = (kt + 1) & 1;
            const int k0 = (kt + 1) << 6;
#pragma unroll
            for (int g = 0; g < 4; g++)
                gl_lds16(Ab + (size_t)g * 32 * K + k0, &As[nb2][(g * 32 + wave * 8) * 64]);
#pragma unroll
            for (int g = 0; g < 2; g++)
                gl_lds16(Bb + (size_t)g * 32 * K + k0, &Bs[nb2][(g * 32 + wave * 8) * 64]);
        }
        const unsigned short* A_ = As[kt & 1];
        const unsigned short* B_ = Bs[kt & 1];
#pragma unroll
        for (int ks = 0; ks < 2; ks++) {
            const int ch = (ks * 4 + quad) ^ (m16 & 7);
            bf16x8 af[4], bfr[2];
#pragma unroll
            for (int mb = 0; mb < 4; mb++)
                af[mb] = *(const bf16x8*)&A_[(wm + mb * 16 + m16) * 64 + ch * 8];
#pragma unroll
            for (int nb = 0; nb < 2; nb++)
                bfr[nb] = *(const bf16x8*)&B_[(wn + nb * 16 + m16) * 64 + ch * 8];
#pragma unroll
            for (int mb = 0; mb < 4; mb++)
#pragma unroll
                for (int nb = 0; nb < 2; nb++)
                    acc[mb][nb] = __builtin_amdgcn_mfma_f32_16x16x32_bf16(af[mb], bfr[nb], acc[mb][nb], 0, 0, 0);
        }
    }

    if (c_bf16) {
        unsigned short* C = (unsigned short*)Cv;
#pragma unroll
        for (int mb = 0; mb < 4; mb++)
#pragma unroll
            for (int nb = 0; nb < 2; nb++)
#pragma unroll
                for (int r = 0; r < 4; r++)
                    C[(size_t)(m0 + wm + mb * 16 + quad * 4 + r) * N + n0 + wn + nb * 16 + m16] =
                        bf16_of(acc[mb][nb][r]);
    } else {
        float* C = (float*)Cv;
#pragma unroll
        for (int mb = 0; mb < 4; mb++)
#pragma unroll
            for (int nb = 0; nb < 2; nb++)
#pragma unroll
                for (int r = 0; r < 4; r++)
                    C[(size_t)(m0 + wm + mb * 16 + quad * 4 + r) * N + n0 + wn + nb * 16 + m16] =
                        acc[mb][nb][r];
    }
}

// ---------------------------------------------------------------------------
// rope_kv: K-RoPE (blocks 0..511) + V transpose-with-key-permute
// (blocks 512..767).  Q-RoPE lives in the attention prologue.
// ---------------------------------------------------------------------------
__global__ __launch_bounds__(256) void rope_kv(const unsigned short* __restrict__ qkv,
                                               unsigned short* __restrict__ kbf,
                                               unsigned short* __restrict__ vbt,
                                               const float* __restrict__ fcos,
                                               const float* __restrict__ fsin) {
    __shared__ unsigned short tile[64][65];
    const int t = threadIdx.x;
    int b = blockIdx.x;
    if (b < 512) {
        int idx = b * 256 + t;
        int s = idx >> 6;
        int rem = idx & 63;
        int hh = rem >> 3, j = rem & 7;
        int srcoff = s * QKV_N + DIM + hh * 64 + j * 8;
        int dstoff = s * KV_DIM + hh * 64 + j * 8;
        bf16x8 v8 = *(const bf16x8*)&qkv[srcoff];
        float4 c4 = *(const float4*)&fcos[s * 32 + j * 4];
        float4 s4 = *(const float4*)&fsin[s * 32 + j * 4];
        float cs[4] = {c4.x, c4.y, c4.z, c4.w};
        float sn[4] = {s4.x, s4.y, s4.z, s4.w};
        bf16x8 o;
#pragma unroll
        for (int p = 0; p < 4; p++) {
            float a = f_of_bf16((unsigned short)v8[2 * p]);
            float bb = f_of_bf16((unsigned short)v8[2 * p + 1]);
            o[2 * p]     = (short)bf16_of(a * cs[p] - bb * sn[p]);
            o[2 * p + 1] = (short)bf16_of(a * sn[p] + bb * cs[p]);
        }
        *(bf16x8*)&kbf[dstoff] = o;
        return;
    }
    b -= 512;                                     // 0..255  (8 x 32)
    const int d0 = (b & 7) * 64;
    const int s0 = (b >> 3) * 64;
#pragma unroll
    for (int i = 0; i < 16; i++) {
        int idx = t + i * 256;
        int r = idx >> 6, c = idx & 63;
        tile[r][c] = qkv[(size_t)(s0 + r) * QKV_N + DIM + KV_DIM + d0 + c];
    }
    __syncthreads();
#pragma unroll
    for (int i = 0; i < 16; i++) {
        int idx = t + i * 256;
        int r = idx >> 6, c = idx & 63;
        int key = s0 + c;
        int kl = key & 127;
        int kp = (kl & 0x60) | ((kl & 0x0C) << 1) | ((kl & 0x10) >> 2) | (kl & 3);
        vbt[(size_t)(d0 + r) * S_LEN + (key & ~127) + kp] = tile[c][r];
    }
}

// ---------------------------------------------------------------------------
// Flash attention v10: QBLK 64 -> 128 with K/V-fragment REUSE.
// Diagnosis (v9 arithmetic): per-CU 272 wave-iters x 32 ds_read_b128 =
// ~70-100K cy on the CU LDS port — the dominant pipe; all 4 waves read
// IDENTICAL K/V fragments (Q is in registers).  Fix: each wave owns 32
// q-rows (two 16-row subtiles); kf/vf read ONCE, fed to 2 MFMAs ->
// per-q-row LDS traffic halves.  MFMA/VALU/exp totals unchanged.
// Grid (h, y=0..15) = 512 blocks = 2/CU.  Dispatch model (v7-confirmed):
// same-CU pair = (h,y),(h,y+8); map qt = y<8 ? 15-y : y-8 -> pair qt sums
// = 15 -> every CU gets exactly 17 iters; long blocks dispatch first.
// Counted-vmcnt barriers, K dbuf + V single buf (48KB), as v9.
// ---------------------------------------------------------------------------
__global__ __launch_bounds__(256) void attn_mfma10(const unsigned short* __restrict__ qkv,
                                                   const unsigned short* __restrict__ kb,
                                                   const unsigned short* __restrict__ vbt,
                                                   const float* __restrict__ fcos,
                                                   const float* __restrict__ fsin,
                                                   unsigned short* __restrict__ out) {
    const int h  = blockIdx.x;
    const int y  = blockIdx.y;                    // 0..15
    const int qt = (y < 8) ? (15 - y) : (y - 8);  // pair-sum-15 CU balance
    const int kh = h >> 2;
    const int tid  = threadIdx.x;
    const int wave = tid >> 6;
    const int lane = tid & 63;
    const int m16  = lane & 15;
    const int quad = lane >> 4;

    __shared__ unsigned short Ks[2][128 * 64];    // [key][dim], chunk-swizzled (32KB)
    __shared__ unsigned short Vt[64 * 128];       // [dim][key(perm)], single buf (16KB)

    const int lrow8 = lane >> 3;
    const int kc    = (lane & 7) ^ lrow8;
    const int lrow4 = lane >> 4;
    const int vc    = (lane & 15) ^ ((wave * 4 + lrow4) & 7);

    const unsigned short* Kbase = kb + (size_t)kh * 64 + (size_t)(wave * 8 + lrow8) * KV_DIM + kc * 8;
    const unsigned short* Vbase = vbt + (size_t)(kh * 64 + wave * 4 + lrow4) * S_LEN + vc * 8;

    bf16x8 ones;
#pragma unroll
    for (int i = 0; i < 8; i++) ones[i] = (short)0x3F80;   // 1.0 bf16

    const int q0 = qt * 128;
    const int n_iter = qt + 1;

    // ---- fused Q-RoPE prologue: two 16-row subtiles per wave ----
    bf16x8 qa[2][2];                              // [subtile][ks]
#pragma unroll
    for (int s = 0; s < 2; s++) {
        const int qrow = q0 + wave * 32 + s * 16 + m16;
        const unsigned short* qsrc = qkv + (size_t)qrow * QKV_N + h * 64;
#pragma unroll
        for (int ks = 0; ks < 2; ks++) {
            bf16x8 raw = *(const bf16x8*)&qsrc[ks * 32 + quad * 8];
            float4 c4 = *(const float4*)&fcos[qrow * 32 + ks * 16 + quad * 4];
            float4 s4 = *(const float4*)&fsin[qrow * 32 + ks * 16 + quad * 4];
            float cs[4] = {c4.x, c4.y, c4.z, c4.w};
            float sn[4] = {s4.x, s4.y, s4.z, s4.w};
#pragma unroll
            for (int p = 0; p < 4; p++) {
                float a = f_of_bf16((unsigned short)raw[2 * p]);
                float bb = f_of_bf16((unsigned short)raw[2 * p + 1]);
                qa[s][ks][2 * p]     = (short)bf16_of((a * cs[p] - bb * sn[p]) * QSCALE);
                qa[s][ks][2 * p + 1] = (short)bf16_of((a * sn[p] + bb * cs[p]) * QSCALE);
            }
        }
    }

    f32x4 o_acc[2][4];
#pragma unroll
    for (int s = 0; s < 2; s++)
#pragma unroll
        for (int nb = 0; nb < 4; nb++) o_acc[s][nb] = (f32x4){0.f, 0.f, 0.f, 0.f};
    f32x4 l_acc[2] = {(f32x4){0.f, 0.f, 0.f, 0.f}, (f32x4){0.f, 0.f, 0.f, 0.f}};
    float m_s[2] = {-1e30f, -1e30f};

    // prologue: stage K tile 0 into buffer 0
#pragma unroll
    for (int g = 0; g < 4; g++)
        gl_lds16(Kbase + (size_t)(g * 32) * KV_DIM, &Ks[0][(g * 32 + wave * 8) * 64]);

    for (int kt = 0; kt < n_iter; kt++) {
        // [A] K(kt) drained; all waves past PV(kt-1) -> V buffer free
        asm volatile("s_waitcnt vmcnt(0)" ::: "memory");
        __builtin_amdgcn_s_barrier();
        __builtin_amdgcn_sched_barrier(0);

        const int knext = (kt + 1 < n_iter) ? (kt + 1) : kt;   // clamp: uniform vmcnt
#pragma unroll
        for (int g = 0; g < 4; g++)
            gl_lds16(Vbase + (size_t)g * 16 * S_LEN + kt * 128,
                     &Vt[(g * 16 + wave * 4) * 128]);
#pragma unroll
        for (int g = 0; g < 4; g++)
            gl_lds16(Kbase + (size_t)(knext * 128 + g * 32) * KV_DIM,
                     &Ks[(kt + 1) & 1][(g * 32 + wave * 8) * 64]);

        const unsigned short* K_ = Ks[kt & 1];

        // ---- S^T = K Q^T, kf read ONCE per (ks,cb), used by both subtiles ----
        f32x4 sc[2][8];
#pragma unroll
        for (int s = 0; s < 2; s++)
#pragma unroll
            for (int cb = 0; cb < 8; cb++) sc[s][cb] = (f32x4){0.f, 0.f, 0.f, 0.f};
        __builtin_amdgcn_s_setprio(1);
#pragma unroll
        for (int ks = 0; ks < 2; ks++) {
            const int slot = (ks * 4 + quad) ^ (m16 & 7);
#pragma unroll
            for (int cb = 0; cb < 8; cb++) {
                bf16x8 kf = *(const bf16x8*)&K_[(cb * 16 + m16) * 64 + slot * 8];
                sc[0][cb] = __builtin_amdgcn_mfma_f32_16x16x32_bf16(kf, qa[0][ks], sc[0][cb], 0, 0, 0);
                sc[1][cb] = __builtin_amdgcn_mfma_f32_16x16x32_bf16(kf, qa[1][ks], sc[1][cb], 0, 0, 0);
            }
        }
        __builtin_amdgcn_s_setprio(0);

        // ---- causal mask (last tile of this q-tile only) ----
        if (kt == n_iter - 1) {
#pragma unroll
            for (int s = 0; s < 2; s++) {
                const int qrl = q0 + wave * 32 + s * 16 + m16;
#pragma unroll
                for (int cb = 0; cb < 8; cb++) {
                    int key = kt * 128 + cb * 16 + quad * 4;
#pragma unroll
                    for (int r = 0; r < 4; r++)
                        if (key + r > qrl) sc[s][cb][r] = -1e30f;
                }
            }
        }

        // ---- online softmax per subtile (exp2 domain) + pack ----
        unsigned int P01[2][8], P23[2][8];
#pragma unroll
        for (int s = 0; s < 2; s++) {
            float rmax = fmaxf(sc[s][0][0], sc[s][0][1]);
            rmax = max3f(sc[s][0][2], sc[s][0][3], rmax);
#pragma unroll
            for (int cb = 1; cb < 8; cb++) {
                rmax = max3f(sc[s][cb][0], sc[s][cb][1], rmax);
                rmax = max3f(sc[s][cb][2], sc[s][cb][3], rmax);
            }
            rmax = fmaxf(rmax, __shfl_xor(rmax, 16, 64));
            rmax = fmaxf(rmax, __shfl_xor(rmax, 32, 64));

            if (!__all(rmax - m_s[s] <= 8.0f)) {          // defer-max (T13)
                float mnew = fmaxf(m_s[s], rmax);
                float alpha = __builtin_amdgcn_exp2f(m_s[s] - mnew);
                m_s[s] = mnew;
#pragma unroll
                for (int r = 0; r < 4; r++) {
                    float a_r = __shfl(alpha, quad * 4 + r, 64);
#pragma unroll
                    for (int nb = 0; nb < 4; nb++) o_acc[s][nb][r] *= a_r;
                    l_acc[s][r] *= a_r;
                }
            }

#pragma unroll
            for (int cb = 0; cb < 8; cb++)
#pragma unroll
                for (int r = 0; r < 4; r++)
                    sc[s][cb][r] = __builtin_amdgcn_exp2f(sc[s][cb][r] - m_s[s]);

#pragma unroll
            for (int cb = 0; cb < 8; cb++) {
                P01[s][cb] = pack2tr(sc[s][cb][0], sc[s][cb][1]);
                P23[s][cb] = pack2tr(sc[s][cb][2], sc[s][cb][3]);
            }
        }

        // [B] V(kt) landed (oldest 4 of <=8 outstanding); K(kt+1) in flight
        asm volatile("s_waitcnt vmcnt(4)" ::: "memory");
        __builtin_amdgcn_s_barrier();
        __builtin_amdgcn_sched_barrier(0);

        // ---- O += P V, vf read ONCE per (ks,nb), used by both subtiles ----
        __builtin_amdgcn_s_setprio(1);
#pragma unroll
        for (int ks = 0; ks < 4; ks++) {
            union { unsigned int u[4]; bf16x8 v; } pa0, pa1;
            pa0.u[0] = P01[0][2 * ks];     pa0.u[1] = P23[0][2 * ks];
            pa0.u[2] = P01[0][2 * ks + 1]; pa0.u[3] = P23[0][2 * ks + 1];
            pa1.u[0] = P01[1][2 * ks];     pa1.u[1] = P23[1][2 * ks];
            pa1.u[2] = P01[1][2 * ks + 1]; pa1.u[3] = P23[1][2 * ks + 1];
            const int slot = (ks * 4 + quad) ^ (m16 & 7);
#pragma unroll
            for (int nb = 0; nb < 4; nb++) {
                bf16x8 vf = *(const bf16x8*)&Vt[(nb * 16 + m16) * 128 + slot * 8];
                o_acc[0][nb] = __builtin_amdgcn_mfma_f32_16x16x32_bf16(pa0.v, vf, o_acc[0][nb], 0, 0, 0);
                o_acc[1][nb] = __builtin_amdgcn_mfma_f32_16x16x32_bf16(pa1.v, vf, o_acc[1][nb], 0, 0, 0);
            }
            l_acc[0] = __builtin_amdgcn_mfma_f32_16x16x32_bf16(pa0.v, ones, l_acc[0], 0, 0, 0);
            l_acc[1] = __builtin_amdgcn_mfma_f32_16x16x32_bf16(pa1.v, ones, l_acc[1], 0, 0, 0);
        }
        __builtin_amdgcn_s_setprio(0);
    }

    // ---- epilogue: normalize by l (already C-layout), store bf16 ----
#pragma unroll
    for (int s = 0; s < 2; s++) {
        const int ob = q0 + wave * 32 + s * 16 + quad * 4;
#pragma unroll
        for (int r = 0; r < 4; r++) {
            float inv_l = 1.f / l_acc[s][r];
#pragma unroll
            for (int nb = 0; nb < 4; nb++)
                out[(size_t)(ob + r) * DIM + h * 64 + nb * 16 + m16] =
                    bf16_of(o_acc[s][nb][r] * inv_l);
        }
    }
}

// ---------------------------------------------------------------------------
extern "C" void kernel_launch(void* const* d_in, const int* in_sizes, int n_in,
                              void* d_out, int out_size, void* d_ws, size_t ws_size,
                              hipStream_t stream) {
    const float* x    = (const float*)d_in[0];
    const float* wq   = (const float*)d_in[1];
    const float* wk   = (const float*)d_in[2];
    const float* wv   = (const float*)d_in[3];
    const float* wo   = (const float*)d_in[4];
    const float* fcos = (const float*)d_in[5];
    const float* fsin = (const float*)d_in[6];

    char* ws = (char*)d_ws;
    const size_t MB = 1024 * 1024;
    unsigned short* xbf    = (unsigned short*)(ws);             //  8 MB [2048][2048]
    unsigned short* wqkvT  = (unsigned short*)(ws + 8 * MB);    // 12 MB [3072][2048]
    unsigned short* woT    = (unsigned short*)(ws + 20 * MB);   //  8 MB [2048][2048]
    unsigned short* qkvbf  = (unsigned short*)(ws + 28 * MB);   // 12 MB [2048][3072]
    unsigned short* vbt    = (unsigned short*)(ws + 40 * MB);   //  2 MB [512][2048]
    // aliases (producer runs strictly after aliased buffer is dead):
    unsigned short* kbf    = (unsigned short*)(ws + 16 * MB);   //  2 MB (over wqkvT tail)
    unsigned short* attnbf = (unsigned short*)(ws);             //  8 MB (over xbf)

    // 1. convert x + transpose weights (fused, vectorized)
    prep<<<4096 + 2560, 256, 0, stream>>>(x, wq, wk, wv, wo, xbf, wqkvT, woT);

    // 2. fused QKV projection (bf16 out) — 128x64 tile, 2-stage dbuf (3/CU)
    gemm_bt64<<<dim3(QKV_N / 64, S_LEN / 128), 256, 0, stream>>>(xbf, wqkvT, qkvbf,
                                                                 S_LEN, QKV_N, DIM, 1);

    // 3. K-RoPE + V transpose (Q-RoPE fused into attention)
    rope_kv<<<512 + 256, 256, 0, stream>>>(qkvbf, kbf, vbt, fcos, fsin);

    // 4. flash attention v10 (QBLK=128, K/V-frag reuse, pair-sum-15 CU balance)
    attn_mfma10<<<dim3(N_HEADS, 16), 256, 0, stream>>>(qkvbf, kbf, vbt, fcos, fsin, attnbf);

    // 5. output projection (fp32 out) — 128x64 tile, 2-stage dbuf
    gemm_bt64<<<dim3(DIM / 64, S_LEN / 128), 256, 0, stream>>>(attnbf, woT, d_out,
                                                               S_LEN, DIM, DIM, 0);
}

// Round 9
// 213.914 us; speedup vs baseline: 1.1227x; 1.1227x over previous
//
#include <hip/hip_runtime.h>
#include <hip/hip_bf16.h>

#define DIM 2048
#define S_LEN 2048
#define N_HEADS 32
#define N_KV_HEADS 8
#define HEAD_DIM 64
#define KV_DIM (N_KV_HEADS * HEAD_DIM)   // 512
#define QKV_N (DIM + 2 * KV_DIM)         // 3072
#define QSCALE 0.18033688011112042f      // 0.125 * log2(e), folded into Q at rope

typedef __attribute__((ext_vector_type(8))) short bf16x8;
typedef __attribute__((ext_vector_type(4))) float f32x4;

__device__ __forceinline__ unsigned short bf16_of(float f) {
    __hip_bfloat16 h = __float2bfloat16(f);
    return *reinterpret_cast<unsigned short*>(&h);
}
__device__ __forceinline__ float f_of_bf16(unsigned short u) {
    unsigned int x = ((unsigned int)u) << 16;
    return __uint_as_float(x);
}
__device__ __forceinline__ void gl_lds16(const void* g, void* l) {
    __builtin_amdgcn_global_load_lds((const __attribute__((address_space(1))) void*)g,
                                     (__attribute__((address_space(3))) void*)l, 16, 0, 0);
}
// pack two fp32 -> bf16x2 by truncation: one v_perm_b32
__device__ __forceinline__ unsigned int pack2tr(float lo, float hi) {
    return __builtin_amdgcn_perm(__float_as_uint(hi), __float_as_uint(lo), 0x07060302u);
}
// 3-input max in one VALU op (T17)
__device__ __forceinline__ float max3f(float a, float b, float c) {
    float d;
    asm("v_max3_f32 %0, %1, %2, %3" : "=v"(d) : "v"(a), "v"(b), "v"(c));
    return d;
}

// ---------------------------------------------------------------------------
// prep: fused x->bf16 convert (blocks 0..4095) + 4 weight transpose/converts
// (blocks 4096..6655).  All weight transposes land in [N][K=2048] bf16.
// Transpose leg vectorized: float4 loads, ushort4 stores.
// ---------------------------------------------------------------------------
__global__ __launch_bounds__(256) void prep(const float* __restrict__ x,
                                            const float* __restrict__ wq,
                                            const float* __restrict__ wk,
                                            const float* __restrict__ wv,
                                            const float* __restrict__ wo,
                                            unsigned short* __restrict__ xbf,
                                            unsigned short* __restrict__ wqkvT,
                                            unsigned short* __restrict__ woT) {
    __shared__ float tile[64][65];
    const int t = threadIdx.x;
    int b = blockIdx.x;
    if (b < 4096) {
        int idx = b * 256 + t;
        float4 f = ((const float4*)x)[idx];
        ushort4 u;
        u.x = bf16_of(f.x); u.y = bf16_of(f.y); u.z = bf16_of(f.z); u.w = bf16_of(f.w);
        ((ushort4*)xbf)[idx] = u;
        return;
    }
    b -= 4096;
    const float* src;
    unsigned short* dst;
    int src_cols, bx, by;
    if (b < 1024)      { src = wq; dst = wqkvT;                                src_cols = DIM;    bx = b & 31;          by = b >> 5; }
    else if (b < 1280) { src = wk; dst = wqkvT + (size_t)DIM * DIM;            src_cols = KV_DIM; bx = (b - 1024) & 7;  by = (b - 1024) >> 3; }
    else if (b < 1536) { src = wv; dst = wqkvT + (size_t)(DIM + KV_DIM) * DIM; src_cols = KV_DIM; bx = (b - 1280) & 7;  by = (b - 1280) >> 3; }
    else               { src = wo; dst = woT;                                  src_cols = DIM;    bx = (b - 1536) & 31; by = (b - 1536) >> 5; }
    const int c0 = bx * 64, r0 = by * 64;
#pragma unroll
    for (int i = 0; i < 4; i++) {
        int idx = t + i * 256;
        int r = idx >> 4, c4 = (idx & 15) * 4;
        float4 f = *(const float4*)&src[(size_t)(r0 + r) * src_cols + c0 + c4];
        tile[r][c4 + 0] = f.x; tile[r][c4 + 1] = f.y;
        tile[r][c4 + 2] = f.z; tile[r][c4 + 3] = f.w;
    }
    __syncthreads();
#pragma unroll
    for (int i = 0; i < 4; i++) {
        int idx = t + i * 256;
        int rr = idx >> 4, cc = (idx & 15) * 4;
        ushort4 u;
        u.x = bf16_of(tile[cc + 0][rr]);
        u.y = bf16_of(tile[cc + 1][rr]);
        u.z = bf16_of(tile[cc + 2][rr]);
        u.w = bf16_of(tile[cc + 3][rr]);
        *(ushort4*)&dst[(size_t)(c0 + rr) * DIM + r0 + cc] = u;
    }
}

// ---------------------------------------------------------------------------
// bf16 MFMA GEMM, 128(M) x 64(N) tile, BK=64, 4 waves (2x2, each 64x32).
// Two-stage single-barrier dbuf (proven best; 3-stage counted-vmcnt measured
// WORSE 59 vs 40us — do not revisit).  LDS 48KB -> 3 blocks/CU.
// mode 0: fp32 C write (out-proj).
// mode 2: fused QKV epilogue —
//   n0 <  2048          : plain bf16 write to C (Q region, stride N)
//   2048 <= n0 < 2560   : K-RoPE applied in-register (pairs = adjacent m16
//                         lanes -> one shfl_xor(1)), bf16 write to kbf
//   n0 >= 2560          : V transpose-with-key-permute, ushort4 store to vbt
//                         (4 acc rows -> 4 consecutive permuted keys)
// ---------------------------------------------------------------------------
__global__ __launch_bounds__(256) void gemm_bt64(const unsigned short* __restrict__ A,
                                                 const unsigned short* __restrict__ Bt,
                                                 void* __restrict__ Cv,
                                                 unsigned short* __restrict__ kbf,
                                                 unsigned short* __restrict__ vbt,
                                                 const float* __restrict__ fcos,
                                                 const float* __restrict__ fsin,
                                                 int M, int N, int K, int mode) {
    __shared__ unsigned short As[2][128 * 64];
    __shared__ unsigned short Bs[2][64 * 64];
    const int tid = threadIdx.x;
    const int wave = tid >> 6, lane = tid & 63;
    const int m16 = lane & 15, quad = lane >> 4;
    const int m0 = blockIdx.y * 128, n0 = blockIdx.x * 64;
    const int wm = (wave >> 1) * 64, wn = (wave & 1) * 32;

    const int lrow = lane >> 3;
    const int gc = (lane & 7) ^ lrow;
    const unsigned short* Ab = A + (size_t)(m0 + wave * 8 + lrow) * K + gc * 8;
    const unsigned short* Bb = Bt + (size_t)(n0 + wave * 8 + lrow) * K + gc * 8;

    f32x4 acc[4][2];
#pragma unroll
    for (int mb = 0; mb < 4; mb++)
#pragma unroll
        for (int nb = 0; nb < 2; nb++) acc[mb][nb] = (f32x4){0.f, 0.f, 0.f, 0.f};

    // prologue: stage tile 0 into buffer 0
#pragma unroll
    for (int g = 0; g < 4; g++)
        gl_lds16(Ab + (size_t)g * 32 * K, &As[0][(g * 32 + wave * 8) * 64]);
#pragma unroll
    for (int g = 0; g < 2; g++)
        gl_lds16(Bb + (size_t)g * 32 * K, &Bs[0][(g * 32 + wave * 8) * 64]);

    const int nt = K >> 6;
    for (int kt = 0; kt < nt; kt++) {
        __syncthreads();                 // drain own DMA (vmcnt0) + prev reads done
        if (kt + 1 < nt) {
            const int nb2 = (kt + 1) & 1;
            const int k0 = (kt + 1) << 6;
#pragma unroll
            for (int g = 0; g < 4; g++)
                gl_lds16(Ab + (size_t)g * 32 * K + k0, &As[nb2][(g * 32 + wave * 8) * 64]);
#pragma unroll
            for (int g = 0; g < 2; g++)
                gl_lds16(Bb + (size_t)g * 32 * K + k0, &Bs[nb2][(g * 32 + wave * 8) * 64]);
        }
        const unsigned short* A_ = As[kt & 1];
        const unsigned short* B_ = Bs[kt & 1];
#pragma unroll
        for (int ks = 0; ks < 2; ks++) {
            const int ch = (ks * 4 + quad) ^ (m16 & 7);
            bf16x8 af[4], bfr[2];
#pragma unroll
            for (int mb = 0; mb < 4; mb++)
                af[mb] = *(const bf16x8*)&A_[(wm + mb * 16 + m16) * 64 + ch * 8];
#pragma unroll
            for (int nb = 0; nb < 2; nb++)
                bfr[nb] = *(const bf16x8*)&B_[(wn + nb * 16 + m16) * 64 + ch * 8];
#pragma unroll
            for (int mb = 0; mb < 4; mb++)
#pragma unroll
                for (int nb = 0; nb < 2; nb++)
                    acc[mb][nb] = __builtin_amdgcn_mfma_f32_16x16x32_bf16(af[mb], bfr[nb], acc[mb][nb], 0, 0, 0);
        }
    }

    if (mode == 0) {
        float* C = (float*)Cv;
#pragma unroll
        for (int mb = 0; mb < 4; mb++)
#pragma unroll
            for (int nb = 0; nb < 2; nb++)
#pragma unroll
                for (int r = 0; r < 4; r++)
                    C[(size_t)(m0 + wm + mb * 16 + quad * 4 + r) * N + n0 + wn + nb * 16 + m16] =
                        acc[mb][nb][r];
    } else if (n0 < DIM) {
        // Q region: plain bf16 write (stride N = QKV_N)
        unsigned short* C = (unsigned short*)Cv;
#pragma unroll
        for (int mb = 0; mb < 4; mb++)
#pragma unroll
            for (int nb = 0; nb < 2; nb++)
#pragma unroll
                for (int r = 0; r < 4; r++)
                    C[(size_t)(m0 + wm + mb * 16 + quad * 4 + r) * N + n0 + wn + nb * 16 + m16] =
                        bf16_of(acc[mb][nb][r]);
    } else if (n0 < DIM + KV_DIM) {
        // K region: RoPE in-register.  Pair partner = lane^1 (m16 parity).
        const int even = !(m16 & 1);
#pragma unroll
        for (int mb = 0; mb < 4; mb++)
#pragma unroll
            for (int nb = 0; nb < 2; nb++) {
                const int khd  = n0 - DIM + wn + nb * 16 + m16;
                const int pair = ((wn + nb * 16 + m16) & 63) >> 1;
#pragma unroll
                for (int r = 0; r < 4; r++) {
                    const int s = m0 + wm + mb * 16 + quad * 4 + r;
                    float v = acc[mb][nb][r];
                    float p = __shfl_xor(v, 1, 64);
                    float c  = fcos[s * 32 + pair];
                    float sn = fsin[s * 32 + pair];
                    float res = even ? (v * c - p * sn) : (v * c + p * sn);
                    kbf[(size_t)s * KV_DIM + khd] = bf16_of(res);
                }
            }
    } else {
        // V region: transpose with key-permute; 4 rows -> consecutive kp | r.
#pragma unroll
        for (int mb = 0; mb < 4; mb++)
#pragma unroll
            for (int nb = 0; nb < 2; nb++) {
                const int d = n0 - DIM - KV_DIM + wn + nb * 16 + m16;
                const int sbase = m0 + wm + mb * 16 + quad * 4;
                const int kl = sbase & 127;
                const int kpb = (kl & 0x60) | ((kl & 0x0C) << 1) | ((kl & 0x10) >> 2);
                ushort4 u;
                u.x = bf16_of(acc[mb][nb][0]);
                u.y = bf16_of(acc[mb][nb][1]);
                u.z = bf16_of(acc[mb][nb][2]);
                u.w = bf16_of(acc[mb][nb][3]);
                *(ushort4*)&vbt[(size_t)d * S_LEN + (sbase & ~127) + kpb] = u;
            }
    }
}

// ---------------------------------------------------------------------------
// Flash attention v9b (round-7 proven, ~36us): fused Q-RoPE prologue (reads
// raw qkvbf), KVBLK=128, K dbuf + V single buf (48KB -> 3 blocks/CU), LPT
// dispatch (h fastest, qt = 31 - y, 1024 blocks backfill), counted-vmcnt
// barriers.  QBLK=128 reuse variant (v10) measured WORSE (63us: 2 blocks/CU
// no-backfill imbalance) — attn geometry is at its floor, do not revisit.
// ---------------------------------------------------------------------------
__global__ __launch_bounds__(256) void attn_mfma9(const unsigned short* __restrict__ qkv,
                                                  const unsigned short* __restrict__ kb,
                                                  const unsigned short* __restrict__ vbt,
                                                  const float* __restrict__ fcos,
                                                  const float* __restrict__ fsin,
                                                  unsigned short* __restrict__ out) {
    const int h  = blockIdx.x;                    // fastest-varying: LPT across heads
    const int qt = 31 - (int)blockIdx.y;          // y=0 -> longest q-tile
    const int kh = h >> 2;
    const int tid  = threadIdx.x;
    const int wave = tid >> 6;
    const int lane = tid & 63;
    const int m16  = lane & 15;
    const int quad = lane >> 4;

    __shared__ unsigned short Ks[2][128 * 64];    // [key][dim], chunk-swizzled (32KB)
    __shared__ unsigned short Vt[64 * 128];       // [dim][key(perm)], single buf (16KB)

    const int lrow8 = lane >> 3;
    const int kc    = (lane & 7) ^ lrow8;
    const int lrow4 = lane >> 4;
    const int vc    = (lane & 15) ^ ((wave * 4 + lrow4) & 7);

    const unsigned short* Kbase = kb + (size_t)kh * 64 + (size_t)(wave * 8 + lrow8) * KV_DIM + kc * 8;
    const unsigned short* Vbase = vbt + (size_t)(kh * 64 + wave * 4 + lrow4) * S_LEN + vc * 8;

    bf16x8 ones;
#pragma unroll
    for (int i = 0; i < 8; i++) ones[i] = (short)0x3F80;   // 1.0 bf16

    const int q0 = qt * 64;
    const int n_iter = (qt >> 1) + 1;

    // ---- fused Q-RoPE prologue (lane-local pairs) ----
    bf16x8 qa[2];
    {
        const int qrow = q0 + wave * 16 + m16;
        const unsigned short* qsrc = qkv + (size_t)qrow * QKV_N + h * 64;
#pragma unroll
        for (int ks = 0; ks < 2; ks++) {
            bf16x8 raw = *(const bf16x8*)&qsrc[ks * 32 + quad * 8];
            float4 c4 = *(const float4*)&fcos[qrow * 32 + ks * 16 + quad * 4];
            float4 s4 = *(const float4*)&fsin[qrow * 32 + ks * 16 + quad * 4];
            float cs[4] = {c4.x, c4.y, c4.z, c4.w};
            float sn[4] = {s4.x, s4.y, s4.z, s4.w};
#pragma unroll
            for (int p = 0; p < 4; p++) {
                float a = f_of_bf16((unsigned short)raw[2 * p]);
                float bb = f_of_bf16((unsigned short)raw[2 * p + 1]);
                qa[ks][2 * p]     = (short)bf16_of((a * cs[p] - bb * sn[p]) * QSCALE);
                qa[ks][2 * p + 1] = (short)bf16_of((a * sn[p] + bb * cs[p]) * QSCALE);
            }
        }
    }

    f32x4 o_acc[4];
#pragma unroll
    for (int nb = 0; nb < 4; nb++) o_acc[nb] = (f32x4){0.f, 0.f, 0.f, 0.f};
    f32x4 l_acc = (f32x4){0.f, 0.f, 0.f, 0.f};
    float m_s = -1e30f;
    const int qrow_lane = q0 + wave * 16 + m16;
    const int orow_base = q0 + wave * 16 + quad * 4;

    // prologue: stage K tile 0 into buffer 0
#pragma unroll
    for (int g = 0; g < 4; g++)
        gl_lds16(Kbase + (size_t)(g * 32) * KV_DIM, &Ks[0][(g * 32 + wave * 8) * 64]);

    for (int kt = 0; kt < n_iter; kt++) {
        // [A] K(kt) drained; all waves past PV(kt-1) -> V buffer free
        asm volatile("s_waitcnt vmcnt(0)" ::: "memory");
        __builtin_amdgcn_s_barrier();
        __builtin_amdgcn_sched_barrier(0);

        const int knext = (kt + 1 < n_iter) ? (kt + 1) : kt;   // clamp: uniform vmcnt
#pragma unroll
        for (int g = 0; g < 4; g++)
            gl_lds16(Vbase + (size_t)g * 16 * S_LEN + kt * 128,
                     &Vt[(g * 16 + wave * 4) * 128]);
#pragma unroll
        for (int g = 0; g < 4; g++)
            gl_lds16(Kbase + (size_t)(knext * 128 + g * 32) * KV_DIM,
                     &Ks[(kt + 1) & 1][(g * 32 + wave * 8) * 64]);

        const unsigned short* K_ = Ks[kt & 1];

        // ---- S^T = K Q^T : sc[cb] holds keys cb*16+quad*4+r, qrow m16 ----
        f32x4 sc[8];
#pragma unroll
        for (int cb = 0; cb < 8; cb++) sc[cb] = (f32x4){0.f, 0.f, 0.f, 0.f};
        __builtin_amdgcn_s_setprio(1);
#pragma unroll
        for (int ks = 0; ks < 2; ks++) {
            const int slot = (ks * 4 + quad) ^ (m16 & 7);
#pragma unroll
            for (int cb = 0; cb < 8; cb++) {
                bf16x8 kf = *(const bf16x8*)&K_[(cb * 16 + m16) * 64 + slot * 8];
                sc[cb] = __builtin_amdgcn_mfma_f32_16x16x32_bf16(kf, qa[ks], sc[cb], 0, 0, 0);
            }
        }
        __builtin_amdgcn_s_setprio(0);

        // ---- causal mask (last tile of this q-tile only) ----
        if (kt == n_iter - 1) {
#pragma unroll
            for (int cb = 0; cb < 8; cb++) {
                int key = kt * 128 + cb * 16 + quad * 4;
#pragma unroll
                for (int r = 0; r < 4; r++)
                    if (key + r > qrow_lane) sc[cb][r] = -1e30f;
            }
        }

        // ---- online softmax (exp2 domain; all 32 values are row m16) ----
        float rmax = fmaxf(sc[0][0], sc[0][1]);
        rmax = max3f(sc[0][2], sc[0][3], rmax);
#pragma unroll
        for (int cb = 1; cb < 8; cb++) {
            rmax = max3f(sc[cb][0], sc[cb][1], rmax);
            rmax = max3f(sc[cb][2], sc[cb][3], rmax);
        }
        rmax = fmaxf(rmax, __shfl_xor(rmax, 16, 64));
        rmax = fmaxf(rmax, __shfl_xor(rmax, 32, 64));

        // defer-max (T13)
        if (!__all(rmax - m_s <= 8.0f)) {
            float mnew = fmaxf(m_s, rmax);
            float alpha = __builtin_amdgcn_exp2f(m_s - mnew);
            m_s = mnew;
#pragma unroll
            for (int r = 0; r < 4; r++) {
                float a_r = __shfl(alpha, quad * 4 + r, 64);
#pragma unroll
                for (int nb = 0; nb < 4; nb++) o_acc[nb][r] *= a_r;
                l_acc[r] *= a_r;
            }
        }

#pragma unroll
        for (int cb = 0; cb < 8; cb++)
#pragma unroll
            for (int r = 0; r < 4; r++)
                sc[cb][r] = __builtin_amdgcn_exp2f(sc[cb][r] - m_s);

        // ---- pack P fragments (truncation, 1 v_perm each) ----
        unsigned int P01[8], P23[8];
#pragma unroll
        for (int cb = 0; cb < 8; cb++) {
            P01[cb] = pack2tr(sc[cb][0], sc[cb][1]);
            P23[cb] = pack2tr(sc[cb][2], sc[cb][3]);
        }

        // [B] V(kt) landed (oldest 4 of <=8 outstanding); K(kt+1) in flight
        asm volatile("s_waitcnt vmcnt(4)" ::: "memory");
        __builtin_amdgcn_s_barrier();
        __builtin_amdgcn_sched_barrier(0);

        // ---- O += P V (and l += P @ ones) ----
        __builtin_amdgcn_s_setprio(1);
#pragma unroll
        for (int ks = 0; ks < 4; ks++) {
            union { unsigned int u[4]; bf16x8 v; } pa;
            pa.u[0] = P01[2 * ks];     pa.u[1] = P23[2 * ks];
            pa.u[2] = P01[2 * ks + 1]; pa.u[3] = P23[2 * ks + 1];
            const int slot = (ks * 4 + quad) ^ (m16 & 7);
#pragma unroll
            for (int nb = 0; nb < 4; nb++) {
                bf16x8 vf = *(const bf16x8*)&Vt[(nb * 16 + m16) * 128 + slot * 8];
                o_acc[nb] = __builtin_amdgcn_mfma_f32_16x16x32_bf16(pa.v, vf, o_acc[nb], 0, 0, 0);
            }
            l_acc = __builtin_amdgcn_mfma_f32_16x16x32_bf16(pa.v, ones, l_acc, 0, 0, 0);
        }
        __builtin_amdgcn_s_setprio(0);
    }

    // ---- epilogue: normalize by l (already C-layout), store bf16 ----
#pragma unroll
    for (int r = 0; r < 4; r++) {
        float inv_l = 1.f / l_acc[r];
#pragma unroll
        for (int nb = 0; nb < 4; nb++)
            out[(size_t)(orow_base + r) * DIM + h * 64 + nb * 16 + m16] =
                bf16_of(o_acc[nb][r] * inv_l);
    }
}

// ---------------------------------------------------------------------------
extern "C" void kernel_launch(void* const* d_in, const int* in_sizes, int n_in,
                              void* d_out, int out_size, void* d_ws, size_t ws_size,
                              hipStream_t stream) {
    const float* x    = (const float*)d_in[0];
    const float* wq   = (const float*)d_in[1];
    const float* wk   = (const float*)d_in[2];
    const float* wv   = (const float*)d_in[3];
    const float* wo   = (const float*)d_in[4];
    const float* fcos = (const float*)d_in[5];
    const float* fsin = (const float*)d_in[6];

    char* ws = (char*)d_ws;
    const size_t MB = 1024 * 1024;
    unsigned short* xbf    = (unsigned short*)(ws);             //  8 MB [2048][2048]
    unsigned short* wqkvT  = (unsigned short*)(ws + 8 * MB);    // 12 MB [3072][2048]
    unsigned short* woT    = (unsigned short*)(ws + 20 * MB);   //  8 MB [2048][2048]
    unsigned short* qkvbf  = (unsigned short*)(ws + 28 * MB);   // 12 MB [2048][3072] (only Q cols written)
    unsigned short* vbt    = (unsigned short*)(ws + 40 * MB);   //  2 MB [512][2048]
    unsigned short* kbf    = (unsigned short*)(ws + 42 * MB);   //  2 MB [2048][512]
    // (kbf must NOT alias wqkvT: the fused GEMM writes it while other blocks
    //  still read K-weights.  Workspace is 256MB per fill counters.)
    unsigned short* attnbf = (unsigned short*)(ws);             //  8 MB (over xbf; QKV gemm done)

    // 1. convert x + transpose weights (fused, vectorized)
    prep<<<4096 + 2560, 256, 0, stream>>>(x, wq, wk, wv, wo, xbf, wqkvT, woT);

    // 2. fused QKV projection + K-RoPE + V-transpose epilogue (mode 2)
    gemm_bt64<<<dim3(QKV_N / 64, S_LEN / 128), 256, 0, stream>>>(
        xbf, wqkvT, qkvbf, kbf, vbt, fcos, fsin, S_LEN, QKV_N, DIM, 2);

    // 3. flash attention v9b (fused Q-RoPE; 48KB LDS, LPT dispatch, counted vmcnt)
    attn_mfma9<<<dim3(N_HEADS, 32), 256, 0, stream>>>(qkvbf, kbf, vbt, fcos, fsin, attnbf);

    // 4. output projection (fp32 out, mode 0)
    gemm_bt64<<<dim3(DIM / 64, S_LEN / 128), 256, 0, stream>>>(
        attnbf, woT, d_out, nullptr, nullptr, nullptr, nullptr, S_LEN, DIM, DIM, 0);
}